// Round 7
// baseline (206.844 us; speedup 1.0000x reference)
//
#include <hip/hip_runtime.h>
#include <cstdint>
#include <cstddef>

#define N_NODES 50000
#define N_EDGES 640000
#define DF 128

#define NBUCK 782          // buckets of 64 nodes: bucket = dst >> 6 (49999>>6 = 781)
#define BCAP  1280         // per-bucket staging cap (mean 818, sigma 28.6 -> +16 sigma)
#define PA_BLOCKS 250      // PassA blocks, 2560 edges each (250*2560 = 640000)

typedef __attribute__((ext_vector_type(8))) short bf16x8;
typedef __attribute__((ext_vector_type(4))) float f32x4;

__device__ inline unsigned short f2bf(float f) {            // RNE float->bf16
    unsigned int u = __float_as_uint(f);
    return (unsigned short)((u + 0x7fffu + ((u >> 16) & 1u)) >> 16);
}
// order-preserving fp32 <-> uint32 (for native uint atomicMax)
__device__ inline unsigned int encf(float f) {
    unsigned int u = __float_as_uint(f);
    return (u & 0x80000000u) ? ~u : (u | 0x80000000u);
}
__device__ inline float decf(unsigned int e) {
    return __uint_as_float((e & 0x80000000u) ? (e & 0x7FFFFFFFu) : ~e);
}

// ================= K1: PassA (64-node buckets) || featb || W frags ===========
// R6 post-mortem: back to R4's validated K1 split (PassA + featb + frags).
// PassA refined to 782 buckets of 64 nodes (dst>>6) so the NEW K3 can
// max-reduce straight out of staging — PassB is DELETED this round.
// blocks [0,250):    PassA — bin 2560 edges into 782 coarse buckets.
// blocks [250,6500): featb = bf16(feat)
// blocks [6500,6524): Wp/Wn1/Wn2 fragments (B-operand order for 16x16x32)
#define NF4 (N_NODES * DF / 4)        // 1,600,000
#define NWG (3 * 2048)
__global__ __launch_bounds__(256) void k1_passa_featb_frags(
    const float* __restrict__ feat,
    const float* __restrict__ W_pool,
    const float* __restrict__ W_neigh,
    const int* __restrict__ src,
    const int* __restrict__ dst,
    const float* __restrict__ w,
    unsigned short* __restrict__ featb,
    unsigned short* __restrict__ Wp_f,
    unsigned short* __restrict__ Wn1_f,
    unsigned short* __restrict__ Wn2_f,
    int* __restrict__ bucketcnt,        // pre-zeroed via hipMemsetAsync
    uint2* __restrict__ staging)
{
    int bid = blockIdx.x;
    int t = threadIdx.x;
    if (bid < PA_BLOCKS) {
        __shared__ int cnt[NBUCK];
        __shared__ int runbase[NBUCK];
        int base = bid * 2560;
        for (int i = t; i < NBUCK; i += 256) cnt[i] = 0;
        __syncthreads();
        uint2 rec[10];
        int bk[10];
        #pragma unroll
        for (int i = 0; i < 10; ++i) {
            int e = base + i * 256 + t;
            int s = src[e], d = dst[e];
            bk[i] = d >> 6;
            rec[i].x = (unsigned int)s | ((unsigned int)(d & 63) << 16);
            rec[i].y = __float_as_uint(w[e]);
            atomicAdd(&cnt[bk[i]], 1);
        }
        __syncthreads();
        for (int i = t; i < NBUCK; i += 256) {
            runbase[i] = atomicAdd(&bucketcnt[i], cnt[i]);
            cnt[i] = 0;                 // reuse as within-run cursor
        }
        __syncthreads();
        #pragma unroll
        for (int i = 0; i < 10; ++i) {
            int r = atomicAdd(&cnt[bk[i]], 1);
            int pos = runbase[bk[i]] + r;
            if (pos < BCAP) staging[(size_t)bk[i] * BCAP + pos] = rec[i];
        }
    } else if (bid < 250 + NF4 / 256) {
        int idx = (bid - PA_BLOCKS) * 256 + t;
        float4 v = ((const float4*)feat)[idx];
        ushort4 o;
        o.x = f2bf(v.x); o.y = f2bf(v.y); o.z = f2bf(v.z); o.w = f2bf(v.w);
        ((ushort4*)featb)[idx] = o;
    } else {
        int g = (bid - PA_BLOCKS - NF4 / 256) * 256 + t;   // < NWG
        int m = g >> 11;
        int r8 = g & 2047;          // (c*4+tt)*64 + L
        int L = r8 & 63, tt = (r8 >> 6) & 3, c = r8 >> 8;
        int o = c * 16 + (L & 15);
        int kb = tt * 32 + (L >> 4) * 8;
        const float* srcp;
        unsigned short* dstp;
        if (m == 0)      { srcp = W_pool  + o * 128 + kb;       dstp = Wp_f;  }
        else if (m == 1) { srcp = W_neigh + o * 256 + kb;       dstp = Wn1_f; }
        else             { srcp = W_neigh + o * 256 + 128 + kb; dstp = Wn2_f; }
        ushort4 lo, hi;
        float4 a = ((const float4*)srcp)[0];
        float4 b = ((const float4*)srcp)[1];
        lo.x = f2bf(a.x); lo.y = f2bf(a.y); lo.z = f2bf(a.z); lo.w = f2bf(a.w);
        hi.x = f2bf(b.x); hi.y = f2bf(b.y); hi.z = f2bf(b.z); hi.w = f2bf(b.w);
        ((ushort4*)(dstp + r8 * 8))[0] = lo;
        ((ushort4*)(dstp + r8 * 8))[1] = hi;
    }
}

// ================= K2: gemm_pool — hb = bf16(featb @ Wp^T + b_pool) ==========
// R4-verbatim GEMM path, standalone (PassB deleted). 782 blocks x 4 waves
// for full-CU spread. Pure streaming: featb 12.8 MB r + hb 12.8 MB w.
__global__ __launch_bounds__(256) void gemm_pool_kernel(
    const unsigned short* __restrict__ featb,
    const unsigned short* __restrict__ Wp_f,
    const float* __restrict__ b_pool,
    unsigned short* __restrict__ hb)
{
    int wave = (blockIdx.x * 256 + threadIdx.x) >> 6;
    int lane = threadIdx.x & 63;
    int m0 = wave * 16;
    if (m0 >= N_NODES) return;
    const int n = lane & 15, quad = lane >> 4;

    f32x4 acc[8];
    #pragma unroll
    for (int c = 0; c < 8; ++c) {
        float bv = b_pool[c * 16 + n];
        acc[c] = (f32x4){bv, bv, bv, bv};
    }
    const unsigned short* aptr = featb + (size_t)(m0 + n) * DF + quad * 8;
    #pragma unroll
    for (int tt = 0; tt < 4; ++tt) {
        bf16x8 af = *(const bf16x8*)(aptr + tt * 32);
        #pragma unroll
        for (int c = 0; c < 8; ++c) {
            bf16x8 bf = *(const bf16x8*)(Wp_f + (size_t)((c * 4 + tt) * 64 + lane) * 8);
            acc[c] = __builtin_amdgcn_mfma_f32_16x16x32_bf16(af, bf, acc[c], 0, 0, 0);
        }
    }
    #pragma unroll
    for (int c = 0; c < 8; ++c)
        #pragma unroll
        for (int r = 0; r < 4; ++r)
            hb[(size_t)(m0 + quad * 4 + r) * DF + c * 16 + n] = f2bf(acc[c][r]);
}

// ========== K3: bucket max-reduce straight from staging (PassB deleted) =====
// One block per 64-node bucket, 512 thr = 8 waves, 32 KB LDS tile of
// order-encoded fp32 (native u32 LDS atomicMax). Each wave: every 8th
// record — full-row 256 B hb gather (4 B/lane, same pattern as the verified
// sorted-gather K3) -> 2 LDS atomicMax/lane (banks dl*128+lane*2: 2-way,
// free per m136). Record loads are affine in i -> pipelined, no dep chain.
// Candidate set identical to R4's fmax chain -> bit-identical output.
__global__ __launch_bounds__(512, 8) void bucket_max_kernel(
    const unsigned short* __restrict__ hb,
    const int* __restrict__ bucketcnt,
    const uint2* __restrict__ staging,
    unsigned short* __restrict__ neighb)
{
    __shared__ unsigned int mx[64 * DF];      // 32 KB encoded fp32 max
    __shared__ int deg[64];
    const int t = threadIdx.x;
    const int b = blockIdx.x;                 // 0..781
    int cnt = bucketcnt[b]; if (cnt > BCAP) cnt = BCAP;

    for (int i = t; i < 64 * DF; i += 512) mx[i] = 0u;   // 0 < enc(any finite)
    if (t < 64) deg[t] = 0;
    __syncthreads();

    const int wid = t >> 6, lane = t & 63;
    for (int i = wid; i < cnt; i += 8) {
        uint2 rec = staging[(size_t)b * BCAP + i];
        int dl = (rec.x >> 16) & 63;
        int s  = rec.x & 0xFFFF;
        float wv = __uint_as_float(rec.y);
        unsigned int p = *(const unsigned int*)(hb + (size_t)s * DF + lane * 2);
        float v0 = __uint_as_float(p << 16)          * wv;
        float v1 = __uint_as_float(p & 0xffff0000u)  * wv;
        atomicMax(&mx[dl * DF + lane * 2],     encf(v0));
        atomicMax(&mx[dl * DF + lane * 2 + 1], encf(v1));
        if (lane == 0) atomicAdd(&deg[dl], 1);
    }
    __syncthreads();

    // write 64 rows x 128 cols bf16, vectorized ushort4 (coalesced)
    for (int j = t; j < 64 * 32; j += 512) {
        int r = j >> 5, c4 = (j & 31) * 4;
        int node = b * 64 + r;
        if (node < N_NODES) {
            bool nz = deg[r] > 0;
            ushort4 ob;
            ob.x = nz ? f2bf(decf(mx[r * DF + c4]))     : (unsigned short)0;
            ob.y = nz ? f2bf(decf(mx[r * DF + c4 + 1])) : (unsigned short)0;
            ob.z = nz ? f2bf(decf(mx[r * DF + c4 + 2])) : (unsigned short)0;
            ob.w = nz ? f2bf(decf(mx[r * DF + c4 + 3])) : (unsigned short)0;
            *(ushort4*)(neighb + (size_t)node * DF + c4) = ob;
        }
    }
}

// ================= K4: out = featb@Wn1^T + neighb@Wn2^T + b_neigh (fp32) ====
__global__ __launch_bounds__(256) void gemm_out(
    const unsigned short* __restrict__ featb,
    const unsigned short* __restrict__ neighb,
    const unsigned short* __restrict__ Wn1_f,
    const unsigned short* __restrict__ Wn2_f,
    const float* __restrict__ bias,
    float* __restrict__ out)
{
    int wave = (blockIdx.x * 256 + threadIdx.x) >> 6;
    int lane = threadIdx.x & 63;
    int m0 = wave * 16;
    if (m0 >= N_NODES) return;
    const int n = lane & 15, quad = lane >> 4;

    f32x4 acc[8];
    #pragma unroll
    for (int c = 0; c < 8; ++c) {
        float bv = bias[c * 16 + n];
        acc[c] = (f32x4){bv, bv, bv, bv};
    }

    const unsigned short* a0 = featb  + (size_t)(m0 + n) * DF + quad * 8;
    const unsigned short* a1 = neighb + (size_t)(m0 + n) * DF + quad * 8;
    #pragma unroll
    for (int t = 0; t < 4; ++t) {
        bf16x8 af = *(const bf16x8*)(a0 + t * 32);
        #pragma unroll
        for (int c = 0; c < 8; ++c) {
            bf16x8 bf = *(const bf16x8*)(Wn1_f + (size_t)((c * 4 + t) * 64 + lane) * 8);
            acc[c] = __builtin_amdgcn_mfma_f32_16x16x32_bf16(af, bf, acc[c], 0, 0, 0);
        }
    }
    #pragma unroll
    for (int t = 0; t < 4; ++t) {
        bf16x8 af = *(const bf16x8*)(a1 + t * 32);
        #pragma unroll
        for (int c = 0; c < 8; ++c) {
            bf16x8 bf = *(const bf16x8*)(Wn2_f + (size_t)((c * 4 + t) * 64 + lane) * 8);
            acc[c] = __builtin_amdgcn_mfma_f32_16x16x32_bf16(af, bf, acc[c], 0, 0, 0);
        }
    }

    #pragma unroll
    for (int c = 0; c < 8; ++c)
        #pragma unroll
        for (int r = 0; r < 4; ++r)
            out[(size_t)(m0 + quad * 4 + r) * DF + c * 16 + n] = acc[c][r];
}

extern "C" void kernel_launch(void* const* d_in, const int* in_sizes, int n_in,
                              void* d_out, int out_size, void* d_ws, size_t ws_size,
                              hipStream_t stream) {
    const float* feat    = (const float*)d_in[0];
    const float* weight  = (const float*)d_in[1];
    const int*   src     = (const int*)d_in[2];
    const int*   dst     = (const int*)d_in[3];
    const float* W_pool  = (const float*)d_in[4];
    const float* b_pool  = (const float*)d_in[5];
    const float* W_neigh = (const float*)d_in[6];
    const float* b_neigh = (const float*)d_in[7];
    float* out = (float*)d_out;

    char* ws = (char*)d_ws;
    unsigned short* featb  = (unsigned short*)(ws);              // 12,800,000 B
    unsigned short* hb     = (unsigned short*)(ws + 12800000);   // 12,800,000 B
    unsigned short* Wp_f   = (unsigned short*)(ws + 25600000);   // 32,768 B
    unsigned short* Wn1_f  = (unsigned short*)(ws + 25632768);   // 32,768 B
    unsigned short* Wn2_f  = (unsigned short*)(ws + 25665536);   // 32,768 B
    int*   bucketcnt = (int*)  (ws + 25698304);                  // 3,200 B
    uint2* staging   = (uint2*)(ws + 25701504);                  // 8,007,680 B
    unsigned short* neighb = (unsigned short*)(ws + 33709184);   // 12,800,000 B -> ~46.5 MB

    hipMemsetAsync(bucketcnt, 0, NBUCK * sizeof(int), stream);

    // K1: PassA (782-bucket coarse sort) || featb conversion || W fragments
    const int K1_BLOCKS = PA_BLOCKS + NF4 / 256 + NWG / 256;   // 250+6250+24
    k1_passa_featb_frags<<<K1_BLOCKS, 256, 0, stream>>>(
        feat, W_pool, W_neigh, src, dst, weight,
        featb, Wp_f, Wn1_f, Wn2_f, bucketcnt, staging);

    // K2: hb = bf16(featb @ Wp^T + b_pool)   (standalone streaming GEMM)
    gemm_pool_kernel<<<782, 256, 0, stream>>>(featb, Wp_f, b_pool, hb);

    // K3: per-bucket LDS max-reduce from staging (replaces PassB + sorted K3)
    bucket_max_kernel<<<NBUCK, 512, 0, stream>>>(hb, bucketcnt, staging, neighb);

    // K4: out = featb @ Wn1^T + neighb @ Wn2^T + b_neigh
    gemm_out<<<782, 256, 0, stream>>>(
        featb, neighb, Wn1_f, Wn2_f, b_neigh, out);
}

// Round 8
// 174.335 us; speedup vs baseline: 1.1865x; 1.1865x over previous
//
#include <hip/hip_runtime.h>
#include <cstdint>
#include <cstddef>

#define N_NODES 50000
#define N_EDGES 640000
#define DF 128

#define NBUCK 782          // buckets of 64 nodes: bucket = dst >> 6
#define BCAP  1280         // per-bucket staging cap (mean 818, +16 sigma)
#define ECAP  1536         // padded per-bucket edge region (max ~950 + 64*7 pad)
#define PA_BLOCKS 250      // PassA blocks, 2560 edges each
#define GEMMB 782          // gemm_pool block-units in K2 (4 waves each)
#define DUMMY_ROW 50000    // hb row = -3.39e38 (pad records point here)

typedef __attribute__((ext_vector_type(8))) short bf16x8;
typedef __attribute__((ext_vector_type(4))) float f32x4;

__device__ inline unsigned short f2bf(float f) {            // RNE float->bf16
    unsigned int u = __float_as_uint(f);
    return (unsigned short)((u + 0x7fffu + ((u >> 16) & 1u)) >> 16);
}

// ================= K1: PassA (782 buckets, R7-validated) || featb || frags ===
// blocks [0,250):    PassA — bin 2560 edges into 782 coarse buckets.
// blocks [250,6500): featb = bf16(feat)
// blocks [6500,6524): Wp/Wn1/Wn2 fragments (B-operand order for 16x16x32)
// block  6524:       hb[DUMMY_ROW] = bf16(-3.39e38)
#define NF4 (N_NODES * DF / 4)        // 1,600,000
#define NWG (3 * 2048)
__global__ __launch_bounds__(256) void k1_passa_featb_frags(
    const float* __restrict__ feat,
    const float* __restrict__ W_pool,
    const float* __restrict__ W_neigh,
    const int* __restrict__ src,
    const int* __restrict__ dst,
    const float* __restrict__ w,
    unsigned short* __restrict__ featb,
    unsigned short* __restrict__ hb,
    unsigned short* __restrict__ Wp_f,
    unsigned short* __restrict__ Wn1_f,
    unsigned short* __restrict__ Wn2_f,
    int* __restrict__ bucketcnt,        // pre-zeroed via hipMemsetAsync
    uint2* __restrict__ staging)
{
    int bid = blockIdx.x;
    int t = threadIdx.x;
    if (bid < PA_BLOCKS) {
        __shared__ int cnt[NBUCK];
        __shared__ int runbase[NBUCK];
        int base = bid * 2560;
        for (int i = t; i < NBUCK; i += 256) cnt[i] = 0;
        __syncthreads();
        uint2 rec[10];
        int bk[10];
        #pragma unroll
        for (int i = 0; i < 10; ++i) {
            int e = base + i * 256 + t;
            int s = src[e], d = dst[e];
            bk[i] = d >> 6;
            rec[i].x = (unsigned int)s | ((unsigned int)(d & 63) << 16);
            rec[i].y = __float_as_uint(w[e]);
            atomicAdd(&cnt[bk[i]], 1);
        }
        __syncthreads();
        for (int i = t; i < NBUCK; i += 256) {
            runbase[i] = atomicAdd(&bucketcnt[i], cnt[i]);
            cnt[i] = 0;                 // reuse as within-run cursor
        }
        __syncthreads();
        #pragma unroll
        for (int i = 0; i < 10; ++i) {
            int r = atomicAdd(&cnt[bk[i]], 1);
            int pos = runbase[bk[i]] + r;
            if (pos < BCAP) staging[(size_t)bk[i] * BCAP + pos] = rec[i];
        }
    } else if (bid < 250 + NF4 / 256) {
        int idx = (bid - PA_BLOCKS) * 256 + t;
        float4 v = ((const float4*)feat)[idx];
        ushort4 o;
        o.x = f2bf(v.x); o.y = f2bf(v.y); o.z = f2bf(v.z); o.w = f2bf(v.w);
        ((ushort4*)featb)[idx] = o;
    } else if (bid < 250 + NF4 / 256 + NWG / 256) {
        int g = (bid - PA_BLOCKS - NF4 / 256) * 256 + t;   // < NWG
        int m = g >> 11;
        int r8 = g & 2047;          // (c*4+tt)*64 + L
        int L = r8 & 63, tt = (r8 >> 6) & 3, c = r8 >> 8;
        int o = c * 16 + (L & 15);
        int kb = tt * 32 + (L >> 4) * 8;
        const float* srcp;
        unsigned short* dstp;
        if (m == 0)      { srcp = W_pool  + o * 128 + kb;       dstp = Wp_f;  }
        else if (m == 1) { srcp = W_neigh + o * 256 + kb;       dstp = Wn1_f; }
        else             { srcp = W_neigh + o * 256 + 128 + kb; dstp = Wn2_f; }
        ushort4 lo, hi;
        float4 a = ((const float4*)srcp)[0];
        float4 b = ((const float4*)srcp)[1];
        lo.x = f2bf(a.x); lo.y = f2bf(a.y); lo.z = f2bf(a.z); lo.w = f2bf(a.w);
        hi.x = f2bf(b.x); hi.y = f2bf(b.y); hi.z = f2bf(b.z); hi.w = f2bf(b.w);
        ((ushort4*)(dstp + r8 * 8))[0] = lo;
        ((ushort4*)(dstp + r8 * 8))[1] = hi;
    } else {
        // dummy hb row: bf16 -3.39e38 — pad-record messages never win the max
        if (t < DF) hb[(size_t)DUMMY_ROW * DF + t] = 0xFF7Fu;
    }
}

// ====== K2: gemm_pool || PassB-64 — re-granulated for full-CU spread ========
// R7 post-mortem diagnosis: R4's PassB ran 196 blocks = 0.77 blocks/CU,
// latency-bound serial chain per block. This round's ONE change: 1564 blocks
// of 256 thr (782 gemm units + 782 fine-bucket PassB units ≈ 6 blocks/CU).
// PassB-64: ~818 records/bucket, per-node scan = 64 elems by ONE WAVE via
// __shfl_up (no barriers). Output format (offsets/nend/padded edges with
// DUMMY_ROW fills) identical to R4 — K3 unchanged.
__global__ __launch_bounds__(256) void k2_gemm_passb(
    const unsigned short* __restrict__ featb,
    const unsigned short* __restrict__ Wp_f,
    const float* __restrict__ b_pool,
    unsigned short* __restrict__ hb,
    const int* __restrict__ bucketcnt,
    const uint2* __restrict__ staging,
    int* __restrict__ offsets,
    int* __restrict__ nend,
    uint2* __restrict__ edges)
{
    int t = threadIdx.x;
    if (blockIdx.x < GEMMB) {
        int wave = blockIdx.x * 4 + (t >> 6);
        int lane = t & 63;
        int m0 = wave * 16;
        if (m0 >= N_NODES) return;          // no barriers on this path
        const int n = lane & 15, quad = lane >> 4;

        f32x4 acc[8];
        #pragma unroll
        for (int c = 0; c < 8; ++c) {
            float bv = b_pool[c * 16 + n];
            acc[c] = (f32x4){bv, bv, bv, bv};
        }
        const unsigned short* aptr = featb + (size_t)(m0 + n) * DF + quad * 8;
        #pragma unroll
        for (int tt = 0; tt < 4; ++tt) {
            bf16x8 af = *(const bf16x8*)(aptr + tt * 32);
            #pragma unroll
            for (int c = 0; c < 8; ++c) {
                bf16x8 bf = *(const bf16x8*)(Wp_f + (size_t)((c * 4 + tt) * 64 + lane) * 8);
                acc[c] = __builtin_amdgcn_mfma_f32_16x16x32_bf16(af, bf, acc[c], 0, 0, 0);
            }
        }
        #pragma unroll
        for (int c = 0; c < 8; ++c)
            #pragma unroll
            for (int r = 0; r < 4; ++r)
                hb[(size_t)(m0 + quad * 4 + r) * DF + c * 16 + n] = f2bf(acc[c][r]);
    } else {
        __shared__ int dcnt[64];        // per-node count, then write cursor
        int b = blockIdx.x - GEMMB;     // 0..781
        int cnt = bucketcnt[b];
        if (cnt > BCAP) cnt = BCAP;     // PassA dropped overflow records

        if (t < 64) dcnt[t] = 0;
        __syncthreads();

        // load my staged records, count per-node degrees
        uint2 rec[5];
        int nit = (cnt + 255) >> 8;
        for (int i = 0; i < nit; ++i) {
            int idx = i * 256 + t;
            if (idx < cnt) {
                rec[i] = staging[(size_t)b * BCAP + idx];
                atomicAdd(&dcnt[(rec[i].x >> 16) & 63], 1);
            }
        }
        __syncthreads();
        // wave 0: pad counts, shfl inclusive scan, offsets/nend, pad fills
        if (t < 64) {
            int mydeg = dcnt[t];
            int mypad = (mydeg + 7) & ~7;       // round up to multiple of 8
            int v = mypad;
            #pragma unroll
            for (int off = 1; off < 64; off <<= 1) {
                int u = __shfl_up(v, off, 64);
                if (t >= off) v += u;
            }
            int beg = b * ECAP + v - mypad;     // exclusive padded prefix
            int node = b * 64 + t;
            if (node < N_NODES) {
                offsets[node] = beg;
                nend[node] = beg + mypad;       // PADDED end — K3 loop bound
            }
            dcnt[t] = beg;                      // repurpose: write cursor
            uint2 dmy; dmy.x = DUMMY_ROW; dmy.y = 0x3F800000u;   // w = 1.0
            for (int k = mydeg; k < mypad; ++k) edges[beg + k] = dmy;
        }
        __syncthreads();
        for (int i = 0; i < nit; ++i) {
            int idx = i * 256 + t;
            if (idx < cnt) {
                int dl = (rec[i].x >> 16) & 63;
                int pos = atomicAdd(&dcnt[dl], 1);
                uint2 fin;
                fin.x = rec[i].x & 0xFFFFu;     // src
                fin.y = rec[i].y;               // w bits
                edges[pos] = fin;
            }
        }
    }
}

// ================= K3: per-node max over incoming messages (1 wave/node) ====
// R4-verbatim. Padded segments (multiple of 8, DUMMY_ROW = -3.39e38, w=1)
// -> no min-clamps, no end bookkeeping. 8-edge / low-VGPR form.
__global__ __launch_bounds__(256) void neigh_max_kernel(
    const unsigned short* __restrict__ hb, const int* __restrict__ offsets,
    const int* __restrict__ nend,
    const uint2* __restrict__ edges,
    unsigned short* __restrict__ neighb)
{
    int gwave = (blockIdx.x * 256 + threadIdx.x) >> 6;
    if (gwave >= N_NODES) return;
    int node = __builtin_amdgcn_readfirstlane(gwave);
    int lane = threadIdx.x & 63;
    const int half = lane >> 5;      // 0: even edge of pair, 1: odd edge
    const int q = lane & 31;         // column quarter: cols 4q..4q+3

    int beg = offsets[node], end = nend[node];   // end is padded (multiple of 8)
    float4 acc = make_float4(-3.4e38f, -3.4e38f, -3.4e38f, -3.4e38f);

    for (int e = beg; e < end; e += 8) {
        uint2 e0 = edges[e],     e1 = edges[e + 1], e2 = edges[e + 2], e3 = edges[e + 3];
        uint2 e4 = edges[e + 4], e5 = edges[e + 5], e6 = edges[e + 6], e7 = edges[e + 7];
        uint2 mA = half ? e1 : e0;
        uint2 mB = half ? e3 : e2;
        uint2 mC = half ? e5 : e4;
        uint2 mD = half ? e7 : e6;
        float wA = __uint_as_float(mA.y);
        float wB = __uint_as_float(mB.y);
        float wC = __uint_as_float(mC.y);
        float wD = __uint_as_float(mD.y);
        uint2 pA = *(const uint2*)(hb + (size_t)mA.x * DF + q * 4);
        uint2 pB = *(const uint2*)(hb + (size_t)mB.x * DF + q * 4);
        uint2 pC = *(const uint2*)(hb + (size_t)mC.x * DF + q * 4);
        uint2 pD = *(const uint2*)(hb + (size_t)mD.x * DF + q * 4);
        acc.x = fmaxf(acc.x, __uint_as_float(pA.x << 16)          * wA);
        acc.y = fmaxf(acc.y, __uint_as_float(pA.x & 0xffff0000u)  * wA);
        acc.z = fmaxf(acc.z, __uint_as_float(pA.y << 16)          * wA);
        acc.w = fmaxf(acc.w, __uint_as_float(pA.y & 0xffff0000u)  * wA);
        acc.x = fmaxf(acc.x, __uint_as_float(pB.x << 16)          * wB);
        acc.y = fmaxf(acc.y, __uint_as_float(pB.x & 0xffff0000u)  * wB);
        acc.z = fmaxf(acc.z, __uint_as_float(pB.y << 16)          * wB);
        acc.w = fmaxf(acc.w, __uint_as_float(pB.y & 0xffff0000u)  * wB);
        acc.x = fmaxf(acc.x, __uint_as_float(pC.x << 16)          * wC);
        acc.y = fmaxf(acc.y, __uint_as_float(pC.x & 0xffff0000u)  * wC);
        acc.z = fmaxf(acc.z, __uint_as_float(pC.y << 16)          * wC);
        acc.w = fmaxf(acc.w, __uint_as_float(pC.y & 0xffff0000u)  * wC);
        acc.x = fmaxf(acc.x, __uint_as_float(pD.x << 16)          * wD);
        acc.y = fmaxf(acc.y, __uint_as_float(pD.x & 0xffff0000u)  * wD);
        acc.z = fmaxf(acc.z, __uint_as_float(pD.y << 16)          * wD);
        acc.w = fmaxf(acc.w, __uint_as_float(pD.y & 0xffff0000u)  * wD);
    }

    float4 o;
    o.x = fmaxf(acc.x, __shfl_xor(acc.x, 32));
    o.y = fmaxf(acc.y, __shfl_xor(acc.y, 32));
    o.z = fmaxf(acc.z, __shfl_xor(acc.z, 32));
    o.w = fmaxf(acc.w, __shfl_xor(acc.w, 32));
    if (beg == end) o = make_float4(0.f, 0.f, 0.f, 0.f);
    if (half == 0) {
        ushort4 ob;
        ob.x = f2bf(o.x); ob.y = f2bf(o.y); ob.z = f2bf(o.z); ob.w = f2bf(o.w);
        *(ushort4*)(neighb + (size_t)node * DF + q * 4) = ob;
    }
}

// ================= K4: out = featb@Wn1^T + neighb@Wn2^T + b_neigh (fp32) ====
__global__ __launch_bounds__(256) void gemm_out(
    const unsigned short* __restrict__ featb,
    const unsigned short* __restrict__ neighb,
    const unsigned short* __restrict__ Wn1_f,
    const unsigned short* __restrict__ Wn2_f,
    const float* __restrict__ bias,
    float* __restrict__ out)
{
    int wave = (blockIdx.x * 256 + threadIdx.x) >> 6;
    int lane = threadIdx.x & 63;
    int m0 = wave * 16;
    if (m0 >= N_NODES) return;
    const int n = lane & 15, quad = lane >> 4;

    f32x4 acc[8];
    #pragma unroll
    for (int c = 0; c < 8; ++c) {
        float bv = bias[c * 16 + n];
        acc[c] = (f32x4){bv, bv, bv, bv};
    }

    const unsigned short* a0 = featb  + (size_t)(m0 + n) * DF + quad * 8;
    const unsigned short* a1 = neighb + (size_t)(m0 + n) * DF + quad * 8;
    #pragma unroll
    for (int t = 0; t < 4; ++t) {
        bf16x8 af = *(const bf16x8*)(a0 + t * 32);
        #pragma unroll
        for (int c = 0; c < 8; ++c) {
            bf16x8 bf = *(const bf16x8*)(Wn1_f + (size_t)((c * 4 + t) * 64 + lane) * 8);
            acc[c] = __builtin_amdgcn_mfma_f32_16x16x32_bf16(af, bf, acc[c], 0, 0, 0);
        }
    }
    #pragma unroll
    for (int t = 0; t < 4; ++t) {
        bf16x8 af = *(const bf16x8*)(a1 + t * 32);
        #pragma unroll
        for (int c = 0; c < 8; ++c) {
            bf16x8 bf = *(const bf16x8*)(Wn2_f + (size_t)((c * 4 + t) * 64 + lane) * 8);
            acc[c] = __builtin_amdgcn_mfma_f32_16x16x32_bf16(af, bf, acc[c], 0, 0, 0);
        }
    }

    #pragma unroll
    for (int c = 0; c < 8; ++c)
        #pragma unroll
        for (int r = 0; r < 4; ++r)
            out[(size_t)(m0 + quad * 4 + r) * DF + c * 16 + n] = acc[c][r];
}

extern "C" void kernel_launch(void* const* d_in, const int* in_sizes, int n_in,
                              void* d_out, int out_size, void* d_ws, size_t ws_size,
                              hipStream_t stream) {
    const float* feat    = (const float*)d_in[0];
    const float* weight  = (const float*)d_in[1];
    const int*   src     = (const int*)d_in[2];
    const int*   dst     = (const int*)d_in[3];
    const float* W_pool  = (const float*)d_in[4];
    const float* b_pool  = (const float*)d_in[5];
    const float* W_neigh = (const float*)d_in[6];
    const float* b_neigh = (const float*)d_in[7];
    float* out = (float*)d_out;

    char* ws = (char*)d_ws;
    unsigned short* featb  = (unsigned short*)(ws);              // 12,800,000 B
    unsigned short* hb     = (unsigned short*)(ws + 12800000);   // 12,800,256 B (50001 rows)
    unsigned short* Wp_f   = (unsigned short*)(ws + 25600512);   // 32,768 B
    unsigned short* Wn1_f  = (unsigned short*)(ws + 25633280);   // 32,768 B
    unsigned short* Wn2_f  = (unsigned short*)(ws + 25666048);   // 32,768 B
    int*   offsets   = (int*)  (ws + 25698816);                  // 200,000 B
    int*   nend      = (int*)  (ws + 25898816);                  // 200,000 B
    int*   bucketcnt = (int*)  (ws + 26098816);                  // 3,200 B
    uint2* staging   = (uint2*)(ws + 26102016);                  // 8,007,680 B (782*1280*8)
    uint2* edges     = (uint2*)(ws + 34109696);                  // 9,609,216 B (782*1536*8)
    unsigned short* neighb = (unsigned short*)(ws + 43718912);   // 12,800,000 B -> ~56.5 MB

    hipMemsetAsync(bucketcnt, 0, NBUCK * sizeof(int), stream);

    // K1: PassA (782-bucket coarse sort) || featb || W frags || dummy row
    const int K1_BLOCKS = PA_BLOCKS + NF4 / 256 + NWG / 256 + 1;   // 6525
    k1_passa_featb_frags<<<K1_BLOCKS, 256, 0, stream>>>(
        feat, W_pool, W_neigh, src, dst, weight,
        featb, hb, Wp_f, Wn1_f, Wn2_f, bucketcnt, staging);

    // K2: gemm_pool (782 units) || PassB-64 (782 buckets) — 1564 blocks
    k2_gemm_passb<<<GEMMB + NBUCK, 256, 0, stream>>>(
        featb, Wp_f, b_pool, hb, bucketcnt, staging, offsets, nend, edges);

    // K3: neighb = bf16(segment_max(hb[src]*w, dst)), 0 for empty
    neigh_max_kernel<<<(N_NODES + 3) / 4, 256, 0, stream>>>(
        hb, offsets, nend, edges, neighb);

    // K4: out = featb @ Wn1^T + neighb @ Wn2^T + b_neigh
    gemm_out<<<782, 256, 0, stream>>>(
        featb, neighb, Wn1_f, Wn2_f, b_neigh, out);
}